// Round 1
// baseline (63.415 us; speedup 1.0000x reference)
//
#include <hip/hip_runtime.h>

#define NPTS   8192
#define BATCH  2
#define CH     64

#define IPT    4          // i's per thread
#define ITILE  (IPT*256)  // 1024 i's per block
#define JTILE  256        // j's per block (staged in LDS)

// ---------------- Kernel 1: Fsim = W @ l0 + b  (SoA fx,fy,fz) ----------------
__global__ __launch_bounds__(256) void fsim_kernel(
    const float* __restrict__ l0,    // [B, C, N]
    const float* __restrict__ W,     // [3, C]
    const float* __restrict__ bias,  // [3]
    float* __restrict__ fx, float* __restrict__ fy, float* __restrict__ fz)
{
    int idx = blockIdx.x * 256 + threadIdx.x;   // 0 .. B*N-1
    int b = idx >> 13;                          // / NPTS
    int n = idx & (NPTS - 1);
    float ax = bias[0], ay = bias[1], az = bias[2];
    const float* base = l0 + (size_t)b * CH * NPTS + n;
    #pragma unroll
    for (int c = 0; c < CH; ++c) {
        float v = base[(size_t)c * NPTS];
        ax = fmaf(W[c],        v, ax);
        ay = fmaf(W[CH + c],   v, ay);
        az = fmaf(W[2*CH + c], v, az);
    }
    fx[idx] = ax; fy[idx] = ay; fz[idx] = az;
}

// ---------------- Kernel 2: tiled pairwise loss ----------------
__global__ __launch_bounds__(256) void pair_kernel(
    const float* __restrict__ fx, const float* __restrict__ fy,
    const float* __restrict__ fz, const int* __restrict__ target,
    double* __restrict__ partials)
{
    __shared__ float4 sj[JTILE];
    const int jt  = blockIdx.x;   // 0..31
    const int it  = blockIdx.y;   // 0..7
    const int b   = blockIdx.z;   // 0..1
    const int tid = threadIdx.x;
    const int base = b * NPTS;

    // i-data in registers
    float ix[IPT], iy[IPT], iz[IPT];
    int   il[IPT];
    #pragma unroll
    for (int u = 0; u < IPT; ++u) {
        int i = it * ITILE + u * 256 + tid;
        ix[u] = fx[base + i]; iy[u] = fy[base + i]; iz[u] = fz[base + i];
        int l = target[base + i];
        il[u] = (l == -1) ? 0x7fffffff : l;   // sentinel: never matches any lj
    }

    // stage j-tile into LDS (one float4 per thread)
    {
        int k = jt * JTILE + tid;
        sj[tid] = make_float4(fx[base + k], fy[base + k], fz[base + k],
                              __int_as_float(target[base + k]));
    }
    __syncthreads();

    float acc = 0.0f;
    #pragma unroll 4
    for (int j = 0; j < JTILE; ++j) {
        float4 q = sj[j];                       // broadcast ds_read_b128
        int lj = __float_as_int(q.w);
        #pragma unroll
        for (int u = 0; u < IPT; ++u) {
            float dx = ix[u] - q.x;
            float dy = iy[u] - q.y;
            float dz = iz[u] - q.z;
            float d  = fmaf(dx, dx, fmaf(dy, dy, dz * dz));   // >= 0 by construction
            float t  = d + 1.0f;
            float r  = __builtin_amdgcn_rcpf(t);
            float i2 = r * r;
            float e  = i2 + i2;                 // alpha(=2) * diff * inv_sq
            bool same = (il[u] == lj);          // valid-mask folded via sentinel
            acc += same ? d : e;
        }
    }

    // block reduction -> one double per block
    #pragma unroll
    for (int off = 32; off > 0; off >>= 1)
        acc += __shfl_down(acc, off, 64);
    __shared__ double wsum[4];
    if ((tid & 63) == 0) wsum[tid >> 6] = (double)acc;
    __syncthreads();
    if (tid == 0) {
        double s = wsum[0] + wsum[1] + wsum[2] + wsum[3];
        partials[(b * 8 + it) * 32 + jt] = s;
    }
}

// ---------------- Kernel 3: final reduce + scale ----------------
__global__ __launch_bounds__(256) void finalize_kernel(
    const double* __restrict__ partials, int nPartials,
    const int* __restrict__ target, float* __restrict__ out)
{
    int tid = threadIdx.x;
    double s = 0.0;
    for (int k = tid; k < nPartials; k += 256) s += partials[k];
    int inv = 0;
    for (int k = tid; k < BATCH * NPTS; k += 256) inv += (target[k] == -1) ? 1 : 0;
    #pragma unroll
    for (int off = 32; off > 0; off >>= 1) {
        s   += __shfl_down(s, off, 64);
        inv += __shfl_down(inv, off, 64);
    }
    __shared__ double sd[4];
    __shared__ int    si[4];
    if ((tid & 63) == 0) { sd[tid >> 6] = s; si[tid >> 6] = inv; }
    __syncthreads();
    if (tid == 0) {
        double tot = sd[0] + sd[1] + sd[2] + sd[3];
        int ic = si[0] + si[1] + si[2] + si[3];
        // diag pairs with label==-1: computed 2*inv_sq(0)=2, reference forces 0
        tot -= 2.0 * (double)ic;
        double mean = 100.0 * tot / ((double)BATCH * NPTS * NPTS);
        out[0] = (float)mean;
    }
}

extern "C" void kernel_launch(void* const* d_in, const int* in_sizes, int n_in,
                              void* d_out, int out_size, void* d_ws, size_t ws_size,
                              hipStream_t stream) {
    const float* l0     = (const float*)d_in[0];   // [2,64,8192]
    const float* W      = (const float*)d_in[1];   // [3,64]
    const float* bias   = (const float*)d_in[2];   // [3]
    const int*   target = (const int*)d_in[3];     // [2,8192]
    float* out = (float*)d_out;

    float* fx = (float*)d_ws;
    float* fy = fx + BATCH * NPTS;
    float* fz = fy + BATCH * NPTS;
    double* partials = (double*)((char*)d_ws + 3 * BATCH * NPTS * sizeof(float) + 256);

    fsim_kernel<<<BATCH * NPTS / 256, 256, 0, stream>>>(l0, W, bias, fx, fy, fz);

    dim3 grid(NPTS / JTILE, NPTS / ITILE, BATCH);   // (32, 8, 2) = 512 blocks
    pair_kernel<<<grid, 256, 0, stream>>>(fx, fy, fz, target, partials);

    finalize_kernel<<<1, 256, 0, stream>>>(partials, 512, target, out);
}

// Round 2
// 53.976 us; speedup vs baseline: 1.1749x; 1.1749x over previous
//
#include <hip/hip_runtime.h>

#define NPTS   8192
#define BATCH  2
#define CH     64

#define IPT    4          // i's per thread
#define ITILE  (IPT*256)  // 1024 i's per block
#define JTILE  64         // j's per block (staged in LDS)

// ---------------- Kernel 1: Fsim = W @ l0 + b  (SoA fx,fy,fz) ----------------
// 16 channels/thread, 4 threads/point, shfl-reduce within wave.
// Block = 256 threads = 4 waves = 64 points. Grid = 256 blocks.
__global__ __launch_bounds__(256) void fsim_kernel(
    const float* __restrict__ l0,    // [B, C, N]
    const float* __restrict__ W,     // [3, C]
    const float* __restrict__ bias,  // [3]
    float* __restrict__ fx, float* __restrict__ fy, float* __restrict__ fz)
{
    __shared__ float sW[3 * CH];
    const int tid = threadIdx.x;
    if (tid < 3 * CH) sW[tid] = W[tid];
    __syncthreads();

    const int lane = tid & 63;
    const int wave = tid >> 6;
    const int p    = lane & 15;          // point within wave
    const int cg   = lane >> 4;          // channel group (0..3), 16 ch each
    const int pt   = blockIdx.x * 64 + wave * 16 + p;   // global point
    const int b    = pt >> 13;
    const int n    = pt & (NPTS - 1);

    const float* base = l0 + (size_t)b * CH * NPTS + n;
    float ax = 0.f, ay = 0.f, az = 0.f;
    #pragma unroll
    for (int k = 0; k < 16; ++k) {
        int c = cg * 16 + k;
        float v = base[(size_t)c * NPTS];
        ax = fmaf(sW[c],          v, ax);
        ay = fmaf(sW[CH + c],     v, ay);
        az = fmaf(sW[2*CH + c],   v, az);
    }
    // reduce across the 4 channel groups (lanes p, p+16, p+32, p+48)
    ax += __shfl_down(ax, 32, 64); ay += __shfl_down(ay, 32, 64); az += __shfl_down(az, 32, 64);
    ax += __shfl_down(ax, 16, 64); ay += __shfl_down(ay, 16, 64); az += __shfl_down(az, 16, 64);
    if (cg == 0) {
        fx[pt] = ax + bias[0];
        fy[pt] = ay + bias[1];
        fz[pt] = az + bias[2];
    }
}

// ---------------- Kernel 2: tiled pairwise loss ----------------
__global__ __launch_bounds__(256) void pair_kernel(
    const float* __restrict__ fx, const float* __restrict__ fy,
    const float* __restrict__ fz, const int* __restrict__ target,
    double* __restrict__ partials)
{
    __shared__ float4 sj[JTILE];
    const int jt  = blockIdx.x;   // 0..127
    const int it  = blockIdx.y;   // 0..7
    const int b   = blockIdx.z;   // 0..1
    const int tid = threadIdx.x;
    const int base = b * NPTS;

    // i-data in registers
    float ix[IPT], iy[IPT], iz[IPT];
    int   il[IPT];
    #pragma unroll
    for (int u = 0; u < IPT; ++u) {
        int i = it * ITILE + u * 256 + tid;
        ix[u] = fx[base + i]; iy[u] = fy[base + i]; iz[u] = fz[base + i];
        int l = target[base + i];
        il[u] = (l == -1) ? 0x7fffffff : l;   // sentinel: never matches any lj
    }

    // stage j-tile into LDS (float4 {x,y,z,label})
    if (tid < JTILE) {
        int k = jt * JTILE + tid;
        sj[tid] = make_float4(fx[base + k], fy[base + k], fz[base + k],
                              __int_as_float(target[base + k]));
    }
    __syncthreads();

    float acc[IPT] = {0.f, 0.f, 0.f, 0.f};
    #pragma unroll 4
    for (int j = 0; j < JTILE; ++j) {
        float4 q = sj[j];                       // broadcast ds_read_b128
        int lj = __float_as_int(q.w);
        #pragma unroll
        for (int u = 0; u < IPT; ++u) {
            float dx = ix[u] - q.x;
            float dy = iy[u] - q.y;
            float dz = iz[u] - q.z;
            float d  = fmaf(dx, dx, fmaf(dy, dy, dz * dz));   // >= 0 by construction
            float t  = d + 1.0f;
            float r  = __builtin_amdgcn_rcpf(t);
            float i2 = r * r;
            float e  = i2 + i2;                 // alpha(=2) * diff * inv_sq
            bool same = (il[u] == lj);          // valid-mask folded via sentinel
            acc[u] += same ? d : e;
        }
    }
    float accs = (acc[0] + acc[1]) + (acc[2] + acc[3]);

    // block reduction -> one double per block
    #pragma unroll
    for (int off = 32; off > 0; off >>= 1)
        accs += __shfl_down(accs, off, 64);
    __shared__ double wsum[4];
    if ((tid & 63) == 0) wsum[tid >> 6] = (double)accs;
    __syncthreads();
    if (tid == 0) {
        double s = wsum[0] + wsum[1] + wsum[2] + wsum[3];
        partials[(b * 8 + it) * 128 + jt] = s;
    }
}

// ---------------- Kernel 3: final reduce + scale ----------------
__global__ __launch_bounds__(256) void finalize_kernel(
    const double* __restrict__ partials, int nPartials,
    const int* __restrict__ target, float* __restrict__ out)
{
    int tid = threadIdx.x;
    double s = 0.0;
    for (int k = tid; k < nPartials; k += 256) s += partials[k];
    int inv = 0;
    for (int k = tid; k < BATCH * NPTS; k += 256) inv += (target[k] == -1) ? 1 : 0;
    #pragma unroll
    for (int off = 32; off > 0; off >>= 1) {
        s   += __shfl_down(s, off, 64);
        inv += __shfl_down(inv, off, 64);
    }
    __shared__ double sd[4];
    __shared__ int    si[4];
    if ((tid & 63) == 0) { sd[tid >> 6] = s; si[tid >> 6] = inv; }
    __syncthreads();
    if (tid == 0) {
        double tot = sd[0] + sd[1] + sd[2] + sd[3];
        int ic = si[0] + si[1] + si[2] + si[3];
        // diag pairs with label==-1: computed 2*inv_sq(0)=2, reference forces 0
        tot -= 2.0 * (double)ic;
        double mean = 100.0 * tot / ((double)BATCH * NPTS * NPTS);
        out[0] = (float)mean;
    }
}

extern "C" void kernel_launch(void* const* d_in, const int* in_sizes, int n_in,
                              void* d_out, int out_size, void* d_ws, size_t ws_size,
                              hipStream_t stream) {
    const float* l0     = (const float*)d_in[0];   // [2,64,8192]
    const float* W      = (const float*)d_in[1];   // [3,64]
    const float* bias   = (const float*)d_in[2];   // [3]
    const int*   target = (const int*)d_in[3];     // [2,8192]
    float* out = (float*)d_out;

    float* fx = (float*)d_ws;
    float* fy = fx + BATCH * NPTS;
    float* fz = fy + BATCH * NPTS;
    double* partials = (double*)((char*)d_ws + 3 * BATCH * NPTS * sizeof(float) + 256);

    fsim_kernel<<<BATCH * NPTS / 64, 256, 0, stream>>>(l0, W, bias, fx, fy, fz);

    dim3 grid(NPTS / JTILE, NPTS / ITILE, BATCH);   // (128, 8, 2) = 2048 blocks
    pair_kernel<<<grid, 256, 0, stream>>>(fx, fy, fz, target, partials);

    finalize_kernel<<<1, 256, 0, stream>>>(partials, 2048, target, out);
}